// Round 11
// baseline (1713.244 us; speedup 1.0000x reference)
//
#include <hip/hip_runtime.h>

#define L_SEQ 2048
#define C_IN  64
#define HH    128
#define NSEQ  32
#define G3    384
#define XW32  (C_IN / 2)                 // 32 u32 per packed x row
#define XTOT  (NSEQ * L_SEQ * XW32)
#define ROWH  136                        // h row: 128 + 8 pad f16 (272 B, 16B-aligned)

typedef _Float16 f16x8 __attribute__((ext_vector_type(8)));
typedef float    f32x4 __attribute__((ext_vector_type(4)));
typedef _Float16 half2_t __attribute__((ext_vector_type(2)));

// per-step barrier: drain LDS only; vmcnt (out stores, x prefetch) floats
#define STEP_BARRIER() asm volatile("s_waitcnt lgkmcnt(0)\n\ts_barrier" ::: "memory")
#define MFMA16(a, b, c) __builtin_amdgcn_mfma_f32_16x16x32_f16((a), (b), (c), 0, 0, 0)

__device__ __forceinline__ unsigned int pack_h2(float a, float b) {
    half2_t t; t.x = (_Float16)a; t.y = (_Float16)b;
    return __builtin_bit_cast(unsigned int, t);
}
__device__ __forceinline__ f16x8 ld_frag_g(const unsigned int* p) {
    return __builtin_bit_cast(f16x8, *(const uint4*)p);
}
__device__ __forceinline__ float fast_sigmoid(float x) {
    float e = __builtin_amdgcn_exp2f(-1.4426950408889634f * x);
    return __builtin_amdgcn_rcpf(1.0f + e);
}
__device__ __forceinline__ float fast_tanh(float x) {
    float a = fabsf(x);
    float e = __builtin_amdgcn_exp2f(-2.8853900817779268f * a);  // e^{-2a}
    float r = (1.0f - e) * __builtin_amdgcn_rcpf(1.0f + e);
    return copysignf(r, x);
}

// ---------------------------------------------------------------------------
// Pre-pass: pack x (f32) -> f16-pair rows in ws, plus one zero row at the end.
// ---------------------------------------------------------------------------
__global__ __launch_bounds__(256)
void pack_x_kernel(const float* __restrict__ x, unsigned int* __restrict__ xh)
{
    const size_t i = (size_t)blockIdx.x * 256 + threadIdx.x;
    if (i < (size_t)XTOT) {
        const float2 v = ((const float2*)x)[i];
        xh[i] = pack_h2(v.x, v.y);
    }
    if (i < XW32) xh[(size_t)XTOT + i] = 0u;     // zero row for ragged tail
}

// ---------------------------------------------------------------------------
// MFMA BiGRU: 4 blocks x 256 threads (4 waves), 16 sequences per block.
// Per step: gates(16x384) = [h(16x128) | x(16x64)] @ W via 16x16x32 f16 MFMA.
//   wave w owns cols [32w,32w+32): r,z fused-K (6 Kt), hn h-only (4 Kt),
//   xn x-only (2 Kt) kept separate because n = tanh(xn + r*hn).
// B frags persistent in VGPRs (144 u32/lane, 256-thr+waves_per_eu(1,1) =
// the proven-resident config). h_old carried in f32 regs (C rows = seqs).
// h exchanged via 8.7 KB double-buffered LDS; ONE lgkm-only barrier/step.
// A layout: row=lane&15, k=(lane>>4)*8+i. B: col=lane&15, same k.
// C/D: col=lane&15, row=(lane>>4)*4+reg  [m89-verified].
// ---------------------------------------------------------------------------
__global__ __launch_bounds__(256) __attribute__((amdgpu_waves_per_eu(1, 1)))
void bigru_mfma(const unsigned int* __restrict__ xh, const int* __restrict__ lengths,
                const float* __restrict__ W_ih, const float* __restrict__ W_hh,
                const float* __restrict__ b_ih, const float* __restrict__ b_hh,
                float* __restrict__ out)
{
    __shared__ _Float16 hlds[2][16][ROWH];

    const int tid = threadIdx.x;
    const int w   = tid >> 6;          // wave 0..3 -> cols [32w, 32w+32)
    const int l   = tid & 63;
    const int lm  = l & 15;            // A row (seq) / B,C col-in-tile
    const int lg  = l >> 4;            // k-group
    const int blk = blockIdx.x;        // 0,1 fwd ; 2,3 rev
    const bool fwd = (blk < 2);

    // ---- persistent B fragments ----
    f16x8 Br[2][6], Bz[2][6], Bhn[2][4], Bxn[2][2];
#pragma unroll
    for (int e = 0; e < 2; ++e) {
        const int col = 32*w + 16*e + lm;
#pragma unroll
        for (int kt = 0; kt < 6; ++kt) {
            f16x8 fr, fz;
#pragma unroll
            for (int i = 0; i < 8; ++i) {
                const int k = kt*32 + lg*8 + i;            // fused K: h then x
                const float vr = (k < HH) ? W_hh[k*G3 + col]
                                          : W_ih[(k-HH)*G3 + col];
                const float vz = (k < HH) ? W_hh[k*G3 + 128 + col]
                                          : W_ih[(k-HH)*G3 + 128 + col];
                fr[i] = (_Float16)vr; fz[i] = (_Float16)vz;
            }
            Br[e][kt] = fr; Bz[e][kt] = fz;
        }
#pragma unroll
        for (int kt = 0; kt < 4; ++kt) {
            f16x8 f;
#pragma unroll
            for (int i = 0; i < 8; ++i)
                f[i] = (_Float16)W_hh[(kt*32 + lg*8 + i)*G3 + 256 + col];
            Bhn[e][kt] = f;
        }
#pragma unroll
        for (int kt = 0; kt < 2; ++kt) {
            f16x8 f;
#pragma unroll
            for (int i = 0; i < 8; ++i)
                f[i] = (_Float16)W_ih[(kt*32 + lg*8 + i)*G3 + 256 + col];
            Bxn[e][kt] = f;
        }
    }
    float biasR[2], biasZ[2], biasHN[2], biasXN[2];
#pragma unroll
    for (int e = 0; e < 2; ++e) {
        const int col = 32*w + 16*e + lm;
        biasR[e]  = b_ih[col] + b_hh[col];
        biasZ[e]  = b_ih[128 + col] + b_hh[128 + col];
        biasHN[e] = b_hh[256 + col];
        biasXN[e] = b_ih[256 + col];
    }

    // ---- x addressing: A rows m = lm ----
    const int sA = 16*(blk & 1) + lm;                 // source seq 0..31
    const unsigned int* __restrict__ xbase = xh + (size_t)sA * L_SEQ * XW32;
    const unsigned int* __restrict__ zrow  = xh + (size_t)XTOT;
    const int lenA = fwd ? 0 : lengths[sA];

    auto xrow = [&](int t) -> const unsigned int* {
        const int src = fwd ? t : (lenA - 1 - t);
        return ((unsigned)src < (unsigned)L_SEQ) ? (xbase + (size_t)src * XW32)
                                                 : zrow;
    };

    // ---- out addressing: C rows m = lg*4 + q ----
    size_t obrow[4];
#pragma unroll
    for (int q = 0; q < 4; ++q)
        obrow[q] = (size_t)(16*(blk & 1) + lg*4 + q) * L_SEQ * 256;
    int colp[2];
#pragma unroll
    for (int e = 0; e < 2; ++e) colp[e] = 32*w + 16*e + lm + (fwd ? 0 : HH);

    // ---- zero h buffers, init h_old regs ----
    f32x4 ho0 = {0.f, 0.f, 0.f, 0.f}, ho1 = {0.f, 0.f, 0.f, 0.f};
    {
        unsigned int* hz = (unsigned int*)&hlds[0][0][0];
        for (int i = tid; i < (int)(sizeof(hlds) / 4); i += 256) hz[i] = 0u;
    }
    __syncthreads();

    // prefetch x frags for t = 0
    f16x8 Ax0, Ax1;
    { const unsigned int* p = xrow(0);
      Ax0 = ld_frag_g(p + lg*4); Ax1 = ld_frag_g(p + 16 + lg*4); }

    int cur = 0;
    for (int t = 0; t < L_SEQ; ++t) {
        // A h-fragments from LDS (row lm, k-slice lg*8 per K-tile)
        const char* hp = (const char*)&hlds[cur][0][0] + lm*(2*ROWH) + lg*16;
        const f16x8 Ah0 = __builtin_bit_cast(f16x8, *(const uint4*)(hp +   0));
        const f16x8 Ah1 = __builtin_bit_cast(f16x8, *(const uint4*)(hp +  64));
        const f16x8 Ah2 = __builtin_bit_cast(f16x8, *(const uint4*)(hp + 128));
        const f16x8 Ah3 = __builtin_bit_cast(f16x8, *(const uint4*)(hp + 192));

        // prefetch next step's x frags (latency hides under MFMA)
        f16x8 AxN0, AxN1;
        { const unsigned int* p = xrow(t + 1);
          AxN0 = ld_frag_g(p + lg*4); AxN1 = ld_frag_g(p + 16 + lg*4); }

        _Float16* hnext = &hlds[cur ^ 1][0][0];

        // ================= e = 0 (cols 32w .. 32w+16) =================
        {
            f32x4 cr = {biasR[0], biasR[0], biasR[0], biasR[0]};
            cr = MFMA16(Ah0, Br[0][0], cr); cr = MFMA16(Ah1, Br[0][1], cr);
            cr = MFMA16(Ah2, Br[0][2], cr); cr = MFMA16(Ah3, Br[0][3], cr);
            cr = MFMA16(Ax0, Br[0][4], cr); cr = MFMA16(Ax1, Br[0][5], cr);
            f32x4 cz = {biasZ[0], biasZ[0], biasZ[0], biasZ[0]};
            cz = MFMA16(Ah0, Bz[0][0], cz); cz = MFMA16(Ah1, Bz[0][1], cz);
            cz = MFMA16(Ah2, Bz[0][2], cz); cz = MFMA16(Ah3, Bz[0][3], cz);
            cz = MFMA16(Ax0, Bz[0][4], cz); cz = MFMA16(Ax1, Bz[0][5], cz);
            f32x4 chn = {biasHN[0], biasHN[0], biasHN[0], biasHN[0]};
            chn = MFMA16(Ah0, Bhn[0][0], chn); chn = MFMA16(Ah1, Bhn[0][1], chn);
            chn = MFMA16(Ah2, Bhn[0][2], chn); chn = MFMA16(Ah3, Bhn[0][3], chn);
            f32x4 cxn = {biasXN[0], biasXN[0], biasXN[0], biasXN[0]};
            cxn = MFMA16(Ax0, Bxn[0][0], cxn); cxn = MFMA16(Ax1, Bxn[0][1], cxn);
#pragma unroll
            for (int q = 0; q < 4; ++q) {
                const float r = fast_sigmoid(cr[q]);
                const float z = fast_sigmoid(cz[q]);
                const float n = fast_tanh(cxn[q] + r * chn[q]);
                const float h = z * (ho0[q] - n) + n;
                ho0[q] = h;
                hnext[(lg*4 + q) * ROWH + (32*w + lm)] = (_Float16)h;
                out[obrow[q] + (size_t)t * 256 + colp[0]] = h;
            }
        }
        // ================= e = 1 (cols 32w+16 .. 32w+32) ==============
        {
            f32x4 cr = {biasR[1], biasR[1], biasR[1], biasR[1]};
            cr = MFMA16(Ah0, Br[1][0], cr); cr = MFMA16(Ah1, Br[1][1], cr);
            cr = MFMA16(Ah2, Br[1][2], cr); cr = MFMA16(Ah3, Br[1][3], cr);
            cr = MFMA16(Ax0, Br[1][4], cr); cr = MFMA16(Ax1, Br[1][5], cr);
            f32x4 cz = {biasZ[1], biasZ[1], biasZ[1], biasZ[1]};
            cz = MFMA16(Ah0, Bz[1][0], cz); cz = MFMA16(Ah1, Bz[1][1], cz);
            cz = MFMA16(Ah2, Bz[1][2], cz); cz = MFMA16(Ah3, Bz[1][3], cz);
            cz = MFMA16(Ax0, Bz[1][4], cz); cz = MFMA16(Ax1, Bz[1][5], cz);
            f32x4 chn = {biasHN[1], biasHN[1], biasHN[1], biasHN[1]};
            chn = MFMA16(Ah0, Bhn[1][0], chn); chn = MFMA16(Ah1, Bhn[1][1], chn);
            chn = MFMA16(Ah2, Bhn[1][2], chn); chn = MFMA16(Ah3, Bhn[1][3], chn);
            f32x4 cxn = {biasXN[1], biasXN[1], biasXN[1], biasXN[1]};
            cxn = MFMA16(Ax0, Bxn[1][0], cxn); cxn = MFMA16(Ax1, Bxn[1][1], cxn);
#pragma unroll
            for (int q = 0; q < 4; ++q) {
                const float r = fast_sigmoid(cr[q]);
                const float z = fast_sigmoid(cz[q]);
                const float n = fast_tanh(cxn[q] + r * chn[q]);
                const float h = z * (ho1[q] - n) + n;
                ho1[q] = h;
                hnext[(lg*4 + q) * ROWH + (32*w + 16 + lm)] = (_Float16)h;
                out[obrow[q] + (size_t)t * 256 + colp[1]] = h;
            }
        }
        STEP_BARRIER();            // h(t+1) buffer ready for all waves
        cur ^= 1;
        Ax0 = AxN0; Ax1 = AxN1;
    }
}

// ---------------------------------------------------------------------------
extern "C" void kernel_launch(void* const* d_in, const int* in_sizes, int n_in,
                              void* d_out, int out_size, void* d_ws, size_t ws_size,
                              hipStream_t stream) {
    const float* x       = (const float*)d_in[0];
    const int*   lengths = (const int*)  d_in[1];
    const float* W_ih    = (const float*)d_in[2];
    const float* W_hh    = (const float*)d_in[3];
    const float* b_ih    = (const float*)d_in[4];
    const float* b_hh    = (const float*)d_in[5];
    float* out = (float*)d_out;

    unsigned int* xh = (unsigned int*)d_ws;      // (XTOT + XW32) u32 = 8.4 MB

    pack_x_kernel<<<dim3((XTOT + 255) / 256), dim3(256), 0, stream>>>(x, xh);
    bigru_mfma<<<dim3(4), dim3(256), 0, stream>>>(
        xh, lengths, W_ih, W_hh, b_ih, b_hh, out);
}

// Round 12
// 1173.285 us; speedup vs baseline: 1.4602x; 1.4602x over previous
//
#include <hip/hip_runtime.h>

#define L_SEQ 2048
#define C_IN  64
#define HH    128
#define NSEQ  32
#define B2    64     // 2*NSEQ sequences (fwd + rev)
#define G3    384    // 3*H
#define T_TILE 128

typedef _Float16 f16x8 __attribute__((ext_vector_type(8)));
typedef float    f32x4 __attribute__((ext_vector_type(4)));

// keep a value opaque + register-resident (defeats rematerialization)
#define PINU(v) asm volatile("" : "+v"(v))
// per-step barrier: drain LDS only; vmcnt (out stores, xw prefetch) floats
#define STEP_BARRIER() asm volatile("s_waitcnt lgkmcnt(0)\n\ts_barrier" ::: "memory")
#define MFMA16(a, b, c) __builtin_amdgcn_mfma_f32_16x16x32_f16((a), (b), (c), 0, 0, 0)

__device__ __forceinline__ float fast_sigmoid(float x) {
    float e = __builtin_amdgcn_exp2f(-1.4426950408889634f * x);
    return __builtin_amdgcn_rcpf(1.0f + e);
}
__device__ __forceinline__ float fast_tanh(float x) {
    float a = fabsf(x);
    float e = __builtin_amdgcn_exp2f(-2.8853900817779268f * a);  // e^{-2a}
    float r = (1.0f - e) * __builtin_amdgcn_rcpf(1.0f + e);
    return copysignf(r, x);
}

// ---------------------------------------------------------------------------
// Kernel 1 (r7-proven): xw[s][tt][j] = bias[j] + sum_c xb[s][t0+tt][c]*W_ih[c][j]
// bias folds b_ih + b_hh for r,z columns (j<256). Block-uniform x rows ->
// s_load broadcast; no LDS. 384 threads, thread = output column j.
// ---------------------------------------------------------------------------
__global__ __launch_bounds__(384)
void xw_kernel(const float* __restrict__ x, const int* __restrict__ lengths,
               const float* __restrict__ W_ih, const float* __restrict__ b_ih,
               const float* __restrict__ b_hh,
               float* __restrict__ xw, int t0, int chunk_steps)
{
    const int tid = threadIdx.x;
    const int tilesPerSeq = chunk_steps / T_TILE;
    const int s    = blockIdx.x / tilesPerSeq;
    const int tile = blockIdx.x % tilesPerSeq;
    const int tbase = t0 + tile * T_TILE;

    const bool isFwd = (s < NSEQ);
    const int  len   = isFwd ? L_SEQ : lengths[s - NSEQ];
    const float* __restrict__ xseq = x + (size_t)(s % NSEQ) * L_SEQ * C_IN;

    const int j = tid;
    float w[64];
#pragma unroll
    for (int q = 0; q < 64; ++q) w[q] = W_ih[q * G3 + j];
#pragma unroll
    for (int q = 0; q < 64; ++q) PINU(w[q]);
    const float bias = b_ih[j] + ((j < 256) ? b_hh[j] : 0.f);

    const int tloc = tile * T_TILE;
#pragma unroll 4
    for (int r = 0; r < T_TILE; ++r) {
        const int t = tbase + r;
        const int src = isFwd ? t : (len - 1 - t);      // block-uniform
        float acc = bias;
        if (src >= 0) {
            const float* __restrict__ xrow = xseq + (size_t)src * C_IN;
#pragma unroll
            for (int q = 0; q < 64; ++q) acc += xrow[q] * w[q];
        }
        xw[((size_t)s * chunk_steps + (tloc + r)) * G3 + j] = acc;
    }
}

// ---------------------------------------------------------------------------
// Kernel 2: MFMA GRU recurrence, ONE sequence per block. 64 blocks x 256
// threads (4 waves). Wave w owns gate columns [32w, 32w+32) of all 3 gates.
// Per step: gates = h(1x128) @ W_hh via mfma_f32_16x16x32_f16, with the
// A-fragment BROADCAST from the single 256 B LDS h-row (all 16 M-rows equal
// -> every lane's C regs hold valid, identical gate sums; no predication).
// 24 MFMA/wave (3 gates x 2 col-tiles x 4 K-tiles); B-frags = 96 VGPR,
// persistent (256-thr + waves_per_eu(1,1) = proven-resident config).
// Epilogue: 2 gate-triples per lane (duplicated across lg groups, uniform);
// lg==0 lanes write h (f16, LDS) and out (f32, global). One lgkm-only
// barrier per step; out-stores and xw prefetch float on vmcnt.
// A/B/C layouts exactly as validated by r11 (passed, absmax 0.0039).
// ---------------------------------------------------------------------------
__global__ __launch_bounds__(256) __attribute__((amdgpu_waves_per_eu(1, 1)))
void gru_mfma(const float* __restrict__ xw, const float* __restrict__ W_hh,
              const float* __restrict__ b_hh, float* __restrict__ out,
              float* __restrict__ hstate, int t0, int chunk_steps)
{
    __shared__ _Float16 hrow[2][HH];     // 256 B per buffer, double-buffered

    const int s   = blockIdx.x;
    const int tid = threadIdx.x;
    const int w   = tid >> 6;            // wave 0..3 -> cols [32w, 32w+32)
    const int l   = tid & 63;
    const int lm  = l & 15;              // col-in-tile
    const int lg  = l >> 4;              // k-group
    const int col0 = 32 * w + lm;
    const int col1 = col0 + 16;
    const bool fwd = (s < NSEQ);

    // persistent B fragments: Bg[e][kt][i] = W_hh[kt*32+lg*8+i][gate*128 + col]
    f16x8 Br[2][4], Bz[2][4], Bn[2][4];
#pragma unroll
    for (int e = 0; e < 2; ++e) {
        const int col = 32 * w + 16 * e + lm;
#pragma unroll
        for (int kt = 0; kt < 4; ++kt) {
            f16x8 fr, fz, fn;
#pragma unroll
            for (int i = 0; i < 8; ++i) {
                const int k = kt * 32 + lg * 8 + i;
                fr[i] = (_Float16)W_hh[k * G3 + col];
                fz[i] = (_Float16)W_hh[k * G3 + 128 + col];
                fn[i] = (_Float16)W_hh[k * G3 + 256 + col];
            }
            Br[e][kt] = fr; Bz[e][kt] = fz; Bn[e][kt] = fn;
        }
    }
    const float bn0 = b_hh[256 + col0];
    const float bn1 = b_hh[256 + col1];

    // h init (h_old carried duplicated in ALL lanes' f32 regs)
    float ho0, ho1;
    if (t0 == 0) {
        ho0 = 0.f; ho1 = 0.f;
        if (tid < HH) hrow[0][tid] = (_Float16)0.f;
    } else {
        ho0 = hstate[s * HH + col0];
        ho1 = hstate[s * HH + col1];
        if (tid < HH) hrow[0][tid] = (_Float16)hstate[s * HH + tid];
    }
    __syncthreads();

    const float* xwp = xw + (size_t)s * chunk_steps * G3;
    // xw for t=0 (6 values; lanes in different lg groups load same addrs)
    float cr0 = xwp[col0], cz0 = xwp[128 + col0], cn0 = xwp[256 + col0];
    float cr1 = xwp[col1], cz1 = xwp[128 + col1], cn1 = xwp[256 + col1];

    float* outbase = out + (size_t)(s % NSEQ) * L_SEQ * 256 + (fwd ? 0 : HH);
    int cur = 0;

    for (int t = 0; t < chunk_steps; ++t) {
        // A fragments: broadcast reads of the h row (uint4 index = kt*4 + lg)
        const uint4* hb = (const uint4*)&hrow[cur][0];
        const f16x8 A0 = __builtin_bit_cast(f16x8, hb[0 * 4 + lg]);
        const f16x8 A1 = __builtin_bit_cast(f16x8, hb[1 * 4 + lg]);
        const f16x8 A2 = __builtin_bit_cast(f16x8, hb[2 * 4 + lg]);
        const f16x8 A3 = __builtin_bit_cast(f16x8, hb[3 * 4 + lg]);

        // prefetch next step's xw (consumed next iteration; vmcnt floats)
        const int tn = (t + 1 < chunk_steps) ? (t + 1) : t;
        const float* qp = xwp + (size_t)tn * G3;
        const float nr0 = qp[col0], nz0 = qp[128 + col0], nn0 = qp[256 + col0];
        const float nr1 = qp[col1], nz1 = qp[128 + col1], nn1 = qp[256 + col1];

        // 6 accumulators x 4-deep K chains (24 MFMA)
        f32x4 ar0 = {0.f,0.f,0.f,0.f}, az0 = {0.f,0.f,0.f,0.f}, an0 = {0.f,0.f,0.f,0.f};
        f32x4 ar1 = {0.f,0.f,0.f,0.f}, az1 = {0.f,0.f,0.f,0.f}, an1 = {0.f,0.f,0.f,0.f};
        ar0 = MFMA16(A0, Br[0][0], ar0); ar0 = MFMA16(A1, Br[0][1], ar0);
        ar0 = MFMA16(A2, Br[0][2], ar0); ar0 = MFMA16(A3, Br[0][3], ar0);
        az0 = MFMA16(A0, Bz[0][0], az0); az0 = MFMA16(A1, Bz[0][1], az0);
        az0 = MFMA16(A2, Bz[0][2], az0); az0 = MFMA16(A3, Bz[0][3], az0);
        an0 = MFMA16(A0, Bn[0][0], an0); an0 = MFMA16(A1, Bn[0][1], an0);
        an0 = MFMA16(A2, Bn[0][2], an0); an0 = MFMA16(A3, Bn[0][3], an0);
        ar1 = MFMA16(A0, Br[1][0], ar1); ar1 = MFMA16(A1, Br[1][1], ar1);
        ar1 = MFMA16(A2, Br[1][2], ar1); ar1 = MFMA16(A3, Br[1][3], ar1);
        az1 = MFMA16(A0, Bz[1][0], az1); az1 = MFMA16(A1, Bz[1][1], az1);
        az1 = MFMA16(A2, Bz[1][2], az1); az1 = MFMA16(A3, Bz[1][3], az1);
        an1 = MFMA16(A0, Bn[1][0], an1); an1 = MFMA16(A1, Bn[1][1], an1);
        an1 = MFMA16(A2, Bn[1][2], an1); an1 = MFMA16(A3, Bn[1][3], an1);

        // gates (all rows equal -> reg 0 is the sequence's value)
        const float r0 = fast_sigmoid(cr0 + ar0[0]);
        const float z0 = fast_sigmoid(cz0 + az0[0]);
        const float n0 = fast_tanh(cn0 + r0 * (an0[0] + bn0));
        const float h0 = z0 * (ho0 - n0) + n0;
        ho0 = h0;
        const float r1 = fast_sigmoid(cr1 + ar1[0]);
        const float z1 = fast_sigmoid(cz1 + az1[0]);
        const float n1 = fast_tanh(cn1 + r1 * (an1[0] + bn1));
        const float h1 = z1 * (ho1 - n1) + n1;
        ho1 = h1;

        if (lg == 0) {
            hrow[cur ^ 1][col0] = (_Float16)h0;
            hrow[cur ^ 1][col1] = (_Float16)h1;
            float* op = outbase + (size_t)(t0 + t) * 256;
            op[col0] = h0;
            op[col1] = h1;
        }
        STEP_BARRIER();
        cur ^= 1;
        cr0 = nr0; cz0 = nz0; cn0 = nn0;
        cr1 = nr1; cz1 = nz1; cn1 = nn1;
    }

    if (t0 + chunk_steps < L_SEQ && lg == 0) {
        hstate[s * HH + col0] = ho0;
        hstate[s * HH + col1] = ho1;
    }
}

// ---------------------------------------------------------------------------
extern "C" void kernel_launch(void* const* d_in, const int* in_sizes, int n_in,
                              void* d_out, int out_size, void* d_ws, size_t ws_size,
                              hipStream_t stream) {
    const float* x       = (const float*)d_in[0];
    const int*   lengths = (const int*)  d_in[1];
    const float* W_ih    = (const float*)d_in[2];
    const float* W_hh    = (const float*)d_in[3];
    const float* b_ih    = (const float*)d_in[4];
    const float* b_hh    = (const float*)d_in[5];
    float* out = (float*)d_out;

    // ws layout: [hstate: B2*HH floats][xw chunk buffer: rest]
    float* hstate = (float*)d_ws;
    float* xw     = hstate + B2 * HH;
    const size_t per_step = (size_t)B2 * G3 * sizeof(float);       // 98304 B
    size_t avail = (ws_size > (size_t)B2 * HH * sizeof(float))
                 ? ws_size - (size_t)B2 * HH * sizeof(float) : 0;
    long long csteps = (long long)(avail / per_step);
    int chunk;
    if (csteps >= L_SEQ)       chunk = L_SEQ;                       // single pass
    else if (csteps >= T_TILE) chunk = (int)((csteps / T_TILE) * T_TILE);
    else                       chunk = T_TILE;                      // best effort

    for (int t0 = 0; t0 < L_SEQ; t0 += chunk) {
        const int steps = (L_SEQ - t0 < chunk) ? (L_SEQ - t0) : chunk;
        xw_kernel<<<dim3((steps / T_TILE) * B2), dim3(384), 0, stream>>>(
            x, lengths, W_ih, b_ih, b_hh, xw, t0, steps);
        gru_mfma<<<dim3(B2), dim3(256), 0, stream>>>(
            xw, W_hh, b_hh, out, hstate, t0, steps);
    }
}